// Round 4
// baseline (298.726 us; speedup 1.0000x reference)
//
#include <hip/hip_runtime.h>

// ZBL screened repulsion + sorted segment sum.
//   d_in[0] Z int32[500000], d_in[1] Dij fp32[16e6], d_in[2] idx_i int32[16e6] (sorted),
//   d_in[3] idx_j int32[16e6], d_in[4] p, d_in[5] d, d_in[6] c[4], d_in[7] a[4]
// Output: fp32[500000] segment_sum over idx_i.
//
// Round 4 (= round-3 theory, compile-fixed): kernel is bound by the 16M random
// z8[idx_j] gathers (~5 cyc per divergent lane-miss in the TCP). Changes:
// (a) EPT 16->8 doubles wave-level parallelism at identical gather/stream
// totals (occupancy was 42%); (b) nontemporal streaming loads stop Dij/idx
// thrash of the 32KB L1 that the z8-table gathers need. i-side gathers stay
// plain (sorted -> ~1 line/wave). nontemporal builtin needs native clang
// vector types (ext_vector_type), not HIP_vector_type float4/int4.

#define EPT   8         // edges per thread (16e6 divisible by 8)
#define BLOCK 256
#define MAXZ  95

typedef float vfloat4 __attribute__((ext_vector_type(4)));
typedef int   vint4   __attribute__((ext_vector_type(4)));

__device__ __forceinline__ float fast_exp2(float x) {
#if __has_builtin(__builtin_amdgcn_exp2f)
    return __builtin_amdgcn_exp2f(x);   // v_exp_f32
#else
    return exp2f(x);
#endif
}

// Stage: compress Z to bytes; compute the 94-entry pow table once.
__global__ void __launch_bounds__(BLOCK) zbl_stage_kernel(
    const int* __restrict__ Z, const float* __restrict__ p,
    unsigned char* __restrict__ z8, float* __restrict__ ptab, int n)
{
    int i = blockIdx.x * BLOCK + threadIdx.x;
    if (i < MAXZ) ptab[i] = powf((float)i, p[0]);   // 0^p = 0, correct
    if (i < n)    z8[i] = (unsigned char)Z[i];
}

__global__ void __launch_bounds__(BLOCK) zbl_edge_kernel(
    const float*         __restrict__ Dij,
    const int*           __restrict__ idx_i,
    const int*           __restrict__ idx_j,
    const unsigned char* __restrict__ z8,
    const float*         __restrict__ ptab_g,
    const float*         __restrict__ dptr,
    const float*         __restrict__ c,
    const float*         __restrict__ a,
    float*               __restrict__ out,
    long long E)
{
    __shared__ float pt[MAXZ + 1];
    for (int k = threadIdx.x; k < MAXZ; k += BLOCK) pt[k] = ptab_g[k];
    __syncthreads();

    const long long t    = (long long)blockIdx.x * BLOCK + threadIdx.x;
    const long long base = t * EPT;
    if (base >= E) return;

    const float LOG2E = 1.4426950408889634f;
    const float invd  = 1.0f / dptr[0];
    const float m0 = -a[0] * LOG2E * invd;
    const float m1 = -a[1] * LOG2E * invd;
    const float m2 = -a[2] * LOG2E * invd;
    const float m3 = -a[3] * LOG2E * invd;
    const float c0 = c[0], c1 = c[1], c2 = c[2], c3 = c[3];

    if (base + EPT <= E) {
        // Phase 1: nontemporal streams (don't pollute L1 -- z8 gathers need it).
        const vfloat4 dq0 = __builtin_nontemporal_load(reinterpret_cast<const vfloat4*>(Dij  + base));
        const vfloat4 dq1 = __builtin_nontemporal_load(reinterpret_cast<const vfloat4*>(Dij  + base + 4));
        const vint4   iq0 = __builtin_nontemporal_load(reinterpret_cast<const vint4*>(idx_i + base));
        const vint4   iq1 = __builtin_nontemporal_load(reinterpret_cast<const vint4*>(idx_i + base + 4));
        const vint4   jq0 = __builtin_nontemporal_load(reinterpret_cast<const vint4*>(idx_j + base));
        const vint4   jq1 = __builtin_nontemporal_load(reinterpret_cast<const vint4*>(idx_j + base + 4));

        float dv[EPT] = {dq0.x, dq0.y, dq0.z, dq0.w, dq1.x, dq1.y, dq1.z, dq1.w};
        int   iv[EPT] = {iq0.x, iq0.y, iq0.z, iq0.w, iq1.x, iq1.y, iq1.z, iq1.w};
        int   jv[EPT] = {jq0.x, jq0.y, jq0.z, jq0.w, jq1.x, jq1.y, jq1.z, jq1.w};

        // Phase 2: issue all gathers (j random -> L2; i sorted -> ~1 line/wave).
        int zi[EPT], zj[EPT];
#pragma unroll
        for (int k = 0; k < EPT; ++k) {
            zj[k] = z8[jv[k]];
            zi[k] = z8[iv[k]];
        }

        // Phase 3: compute + segmented accumulate (idx_i sorted).
        int   cur = iv[0];
        float acc = 0.0f;
#pragma unroll
        for (int k = 0; k < EPT; ++k) {
            const float tt = dv[k] * (pt[zi[k]] + pt[zj[k]]);
            float v;
            v = c0 * fast_exp2(m0 * tt);
            v = fmaf(c1, fast_exp2(m1 * tt), v);
            v = fmaf(c2, fast_exp2(m2 * tt), v);
            v = fmaf(c3, fast_exp2(m3 * tt), v);
            if (iv[k] != cur) { atomicAdd(out + cur, acc); acc = 0.0f; cur = iv[k]; }
            acc += v;
        }
        atomicAdd(out + cur, acc);
    } else {
        int   cur = idx_i[base];
        float acc = 0.0f;
        for (long long e = base; e < E; ++e) {
            const int   i  = idx_i[e];
            const float tt = Dij[e] * (pt[z8[i]] + pt[z8[idx_j[e]]]);
            float v;
            v = c0 * fast_exp2(m0 * tt);
            v = fmaf(c1, fast_exp2(m1 * tt), v);
            v = fmaf(c2, fast_exp2(m2 * tt), v);
            v = fmaf(c3, fast_exp2(m3 * tt), v);
            if (i != cur) { atomicAdd(out + cur, acc); acc = 0.0f; cur = i; }
            acc += v;
        }
        atomicAdd(out + cur, acc);
    }
}

extern "C" void kernel_launch(void* const* d_in, const int* in_sizes, int n_in,
                              void* d_out, int out_size, void* d_ws, size_t ws_size,
                              hipStream_t stream)
{
    const int*   Z     = (const int*)  d_in[0];
    const float* Dij   = (const float*)d_in[1];
    const int*   idx_i = (const int*)  d_in[2];
    const int*   idx_j = (const int*)  d_in[3];
    const float* p     = (const float*)d_in[4];
    const float* d     = (const float*)d_in[5];
    const float* c     = (const float*)d_in[6];
    const float* a     = (const float*)d_in[7];
    float*       out   = (float*)d_out;

    const int       nAtoms = in_sizes[0];
    const long long E      = in_sizes[1];

    // ws layout: [z8: nAtoms bytes][pad to 64][ptab: MAXZ floats]
    unsigned char* z8   = (unsigned char*)d_ws;
    const size_t   poff = ((size_t)nAtoms + 63) & ~(size_t)63;
    float*         ptab = (float*)((char*)d_ws + poff);

    // d_out is re-poisoned 0xAA before every timed launch; we need zeros.
    (void)hipMemsetAsync(d_out, 0, (size_t)out_size * sizeof(float), stream);

    zbl_stage_kernel<<<(nAtoms + BLOCK - 1) / BLOCK, BLOCK, 0, stream>>>(Z, p, z8, ptab, nAtoms);

    const long long nThreads = (E + EPT - 1) / EPT;
    const int       nBlocks  = (int)((nThreads + BLOCK - 1) / BLOCK);
    zbl_edge_kernel<<<nBlocks, BLOCK, 0, stream>>>(Dij, idx_i, idx_j, z8, ptab, d, c, a, out, E);
}

// Round 5
// 257.840 us; speedup vs baseline: 1.1586x; 1.1586x over previous
//
#include <hip/hip_runtime.h>

// ZBL screened repulsion + sorted segment sum.
//   d_in[0] Z int32[500000], d_in[1] Dij fp32[16e6], d_in[2] idx_i int32[16e6] (sorted),
//   d_in[3] idx_j int32[16e6], d_in[4] p, d_in[5] d, d_in[6] c[4], d_in[7] a[4]
// Output: fp32[500000] segment_sum over idx_i.
//
// Round 5: rounds 2/4 showed a ~5.6 cyc/miss invariant cost on the random
// j-gather regardless of occupancy (42% vs 66%) -> throughput bound in the
// per-CU L1 (TCP) miss/allocate/fill/evict path, not latency and not HBM.
// Fix under test: bypass L1 on the j-gather with agent-scope (sc0) loads,
// fetching float zp[j] directly from the L2-resident 2MB table (also deletes
// the j-side LDS lookup). i-side stays a cached byte-gather (sorted -> L1
// hits). Structure reverts to round-2 best: EPT=16, plain vector streams.

#define EPT   16        // edges per thread (16e6 divisible by 16)
#define BLOCK 256
#define MAXZ  95

__device__ __forceinline__ float fast_exp2(float x) {
#if __has_builtin(__builtin_amdgcn_exp2f)
    return __builtin_amdgcn_exp2f(x);   // v_exp_f32
#else
    return exp2f(x);
#endif
}

// Stage: byte-compress Z, build per-atom float zp table and 94-entry pow table.
__global__ void __launch_bounds__(BLOCK) zbl_stage_kernel(
    const int* __restrict__ Z, const float* __restrict__ p,
    unsigned char* __restrict__ z8, float* __restrict__ zpf,
    float* __restrict__ ptab, int n)
{
    int i = blockIdx.x * BLOCK + threadIdx.x;
    if (i < MAXZ) ptab[i] = powf((float)i, p[0]);   // 0^p = 0, correct
    if (i < n) {
        int z = Z[i];
        z8[i]  = (unsigned char)z;
        zpf[i] = powf((float)z, p[0]);
    }
}

__global__ void __launch_bounds__(BLOCK) zbl_edge_kernel(
    const float*         __restrict__ Dij,
    const int*           __restrict__ idx_i,
    const int*           __restrict__ idx_j,
    const unsigned char* __restrict__ z8,
    const float*         __restrict__ zpf,
    const float*         __restrict__ ptab_g,
    const float*         __restrict__ dptr,
    const float*         __restrict__ c,
    const float*         __restrict__ a,
    float*               __restrict__ out,
    long long E)
{
    __shared__ float pt[MAXZ + 1];
    for (int k = threadIdx.x; k < MAXZ; k += BLOCK) pt[k] = ptab_g[k];
    __syncthreads();

    const long long t    = (long long)blockIdx.x * BLOCK + threadIdx.x;
    const long long base = t * EPT;
    if (base >= E) return;

    const float LOG2E = 1.4426950408889634f;
    const float invd  = 1.0f / dptr[0];
    const float m0 = -a[0] * LOG2E * invd;
    const float m1 = -a[1] * LOG2E * invd;
    const float m2 = -a[2] * LOG2E * invd;
    const float m3 = -a[3] * LOG2E * invd;
    const float c0 = c[0], c1 = c[1], c2 = c[2], c3 = c[3];

    if (base + EPT <= E) {
        // Phase 1: coalesced streams into registers (12 x dwordx4).
        float dv[EPT];
        int   iv[EPT], jv[EPT];
#pragma unroll
        for (int v = 0; v < EPT; v += 4) {
            const float4 dq = *reinterpret_cast<const float4*>(Dij  + base + v);
            const int4   iq = *reinterpret_cast<const int4*>(idx_i + base + v);
            const int4   jq = *reinterpret_cast<const int4*>(idx_j + base + v);
            dv[v] = dq.x; dv[v+1] = dq.y; dv[v+2] = dq.z; dv[v+3] = dq.w;
            iv[v] = iq.x; iv[v+1] = iq.y; iv[v+2] = iq.z; iv[v+3] = iq.w;
            jv[v] = jq.x; jv[v+1] = jq.y; jv[v+2] = jq.z; jv[v+3] = jq.w;
        }
        // Phase 2a: j-gathers BYPASS L1 (agent-scope => sc0 => straight to L2).
        float zpj[EPT];
#pragma unroll
        for (int k = 0; k < EPT; ++k) {
            zpj[k] = __hip_atomic_load(zpf + jv[k], __ATOMIC_RELAXED,
                                       __HIP_MEMORY_SCOPE_AGENT);
        }
        // Phase 2b: i-gathers stay cached (sorted -> ~1 line/wave, L1 hits).
        int zi[EPT];
#pragma unroll
        for (int k = 0; k < EPT; ++k) zi[k] = z8[iv[k]];

        // Phase 3: compute + segmented accumulate (idx_i sorted).
        int   cur = iv[0];
        float acc = 0.0f;
#pragma unroll
        for (int k = 0; k < EPT; ++k) {
            const float tt = dv[k] * (pt[zi[k]] + zpj[k]);
            float v;
            v = c0 * fast_exp2(m0 * tt);
            v = fmaf(c1, fast_exp2(m1 * tt), v);
            v = fmaf(c2, fast_exp2(m2 * tt), v);
            v = fmaf(c3, fast_exp2(m3 * tt), v);
            if (iv[k] != cur) { atomicAdd(out + cur, acc); acc = 0.0f; cur = iv[k]; }
            acc += v;
        }
        atomicAdd(out + cur, acc);
    } else {
        int   cur = idx_i[base];
        float acc = 0.0f;
        for (long long e = base; e < E; ++e) {
            const int   i  = idx_i[e];
            const float zj = __hip_atomic_load(zpf + idx_j[e], __ATOMIC_RELAXED,
                                               __HIP_MEMORY_SCOPE_AGENT);
            const float tt = Dij[e] * (pt[z8[i]] + zj);
            float v;
            v = c0 * fast_exp2(m0 * tt);
            v = fmaf(c1, fast_exp2(m1 * tt), v);
            v = fmaf(c2, fast_exp2(m2 * tt), v);
            v = fmaf(c3, fast_exp2(m3 * tt), v);
            if (i != cur) { atomicAdd(out + cur, acc); acc = 0.0f; cur = i; }
            acc += v;
        }
        atomicAdd(out + cur, acc);
    }
}

extern "C" void kernel_launch(void* const* d_in, const int* in_sizes, int n_in,
                              void* d_out, int out_size, void* d_ws, size_t ws_size,
                              hipStream_t stream)
{
    const int*   Z     = (const int*)  d_in[0];
    const float* Dij   = (const float*)d_in[1];
    const int*   idx_i = (const int*)  d_in[2];
    const int*   idx_j = (const int*)  d_in[3];
    const float* p     = (const float*)d_in[4];
    const float* d     = (const float*)d_in[5];
    const float* c     = (const float*)d_in[6];
    const float* a     = (const float*)d_in[7];
    float*       out   = (float*)d_out;

    const int       nAtoms = in_sizes[0];
    const long long E      = in_sizes[1];

    // ws layout: [zpf: nAtoms floats][z8: nAtoms bytes][pad][ptab: MAXZ floats]
    float*         zpf  = (float*)d_ws;
    unsigned char* z8   = (unsigned char*)d_ws + (size_t)nAtoms * sizeof(float);
    size_t         poff = ((size_t)nAtoms * sizeof(float) + (size_t)nAtoms + 63) & ~(size_t)63;
    float*         ptab = (float*)((char*)d_ws + poff);

    // d_out is re-poisoned 0xAA before every timed launch; we need zeros.
    (void)hipMemsetAsync(d_out, 0, (size_t)out_size * sizeof(float), stream);

    zbl_stage_kernel<<<(nAtoms + BLOCK - 1) / BLOCK, BLOCK, 0, stream>>>(
        Z, p, z8, zpf, ptab, nAtoms);

    const long long nThreads = (E + EPT - 1) / EPT;
    const int       nBlocks  = (int)((nThreads + BLOCK - 1) / BLOCK);
    zbl_edge_kernel<<<nBlocks, BLOCK, 0, stream>>>(
        Dij, idx_i, idx_j, z8, zpf, ptab, d, c, a, out, E);
}